// Round 7
// baseline (231.138 us; speedup 1.0000x reference)
//
#include <hip/hip_runtime.h>
#include <stdint.h>

// Problem: N=131072, D=128, W=16, R=5
//   logit[n,r] = e1[n]^T C_r e2[n],  C_r = sum_w weight[w,r] * M_w
//   out[0] = -mean(log_softmax(logit)[n, rels[n]]),  out[1..N] = expected rating
//
// R15: wave-autonomous kernel. R9-R14 bracket: every block-structured variant
//   lands 70-90us, all pipes ~11% -- the {load-wait, barrier, LDS combine}
//   skeleton has an uncoverable serial path at quantization-capped occupancy.
//   Delete the skeleton: ONE WAVE owns 32 rows end-to-end.
//   - B-frags: own e1 rows, global f32->bf16 in regs (32 VGPR, read-once)
//   - e2 pinned (64 VGPR)
//   - A-frags: stream ALL of Cth per wave from L2 (160KB x 4096 waves
//     = 650MB L2 ~ 19us @ 34.5TB/s = the intended new floor)
//   - contract per-et right after its 4 MFMAs -> only 2 accs live
//   - ONLINE softmax over r (m,se,pn,lrel = 8 regs) -> r-loop is a true
//     #pragma unroll 1 loop, no dynamic indexing (rule #20), bounded pressure
//   Zero LDS, zero barriers, zero atomics, zero cross-wave anything.
//   Tells: LDS_Block_Size=0; WRITE_SIZE ~600KB (spill); VGPR 150-190.

#define NTOT 131072
#define DDIM 128
#define WBAS 16
#define RCLS 5
#define ROWS 32                 // rows per wave
#define NTILE (NTOT / ROWS)     // 4096 waves
#define WPB   4                 // waves per block (independent)
#define GRID2 (NTILE / WPB)     // 1024 blocks

typedef __attribute__((ext_vector_type(8))) short bf16x8;
typedef __attribute__((ext_vector_type(4))) float f32x4;

__device__ __forceinline__ unsigned short f2bf(float x) {
    union { float f; unsigned u; } v; v.f = x;
    unsigned u = v.u + 0x7FFFu + ((v.u >> 16) & 1u);
    return (unsigned short)(u >> 16);
}

__device__ __forceinline__ ushort4 f2bf4(float4 v) {
    return make_ushort4(f2bf(v.x), f2bf(v.y), f2bf(v.z), f2bf(v.w));
}

// ---- prep: coalesced read (lanes along e), LDS transpose, bf16 ----
// grid = 80 blocks: r = bx>>4 (5), d-band d0 = (bx&15)*8 (16)
__global__ __launch_bounds__(256) void prep_kernel(
    const float* __restrict__ rel_embeds,    // [W][d][e]
    const float* __restrict__ wsc,           // [W][R]
    unsigned short* __restrict__ Cth)        // [R][e][d] bf16
{
    __shared__ float tile[8][129];
    const int bx = blockIdx.x;
    const int r  = bx >> 4;
    const int d0 = (bx & 15) << 3;
    const int t  = threadIdx.x;

    const int e  = t & 127;     // lanes consecutive in e -> coalesced reads
    const int dl = t >> 7;      // 0..1

    float acc[4] = {0.f, 0.f, 0.f, 0.f};
    for (int w = 0; w < WBAS; ++w) {
        float s = wsc[w * RCLS + r];
#pragma unroll
        for (int dd = 0; dd < 4; ++dd)
            acc[dd] += s * rel_embeds[w * 16384 + (d0 + dd * 2 + dl) * 128 + e];
    }
#pragma unroll
    for (int dd = 0; dd < 4; ++dd) tile[dd * 2 + dl][e] = acc[dd];
    __syncthreads();

    if (t < 128) {          // thread t -> output column e=t, all 8 d of the band
        unsigned short h[8];
#pragma unroll
        for (int j = 0; j < 8; ++j) h[j] = f2bf(tile[j][t]);
        size_t base = (size_t)r * 16384 + (size_t)t * 128 + d0;   // 16B aligned
        *(ushort4*)(Cth + base)     = make_ushort4(h[0], h[1], h[2], h[3]);
        *(ushort4*)(Cth + base + 4) = make_ushort4(h[4], h[5], h[6], h[7]);
    }
}

// ---- main: wave-autonomous, 32 rows per wave, no LDS, no barriers ----
__global__ __launch_bounds__(256, 2) void bilinear_mfma_kernel(
    const float* __restrict__ e1g,           // [N, D]
    const float* __restrict__ e2g,           // [N, D]
    const unsigned short* __restrict__ Cth,  // [R, 128(e), 128(d)] bf16
    const int*   __restrict__ rels,
    float* __restrict__ out,                 // [1 + N]
    float* __restrict__ loss_ws,             // [NTILE] per-wave loss partials
    float inv_n)
{
    const int tid  = threadIdx.x;
    const int lane = tid & 63;
    const int l15  = lane & 15;
    const int q    = lane >> 4;
    const int tile = blockIdx.x * WPB + (tid >> 6);
    const int n0   = tile * ROWS;
    const int na   = n0 + l15;          // lane's row (nt=0)
    const int nb   = n0 + 16 + l15;     // lane's row (nt=1)

    // B-fragments from e1 (f32 -> bf16 in regs): bfr[nt][k4], rows 16nt+l15,
    // k = q*8 + k4*32. Each element of e1 read exactly once chip-wide.
    bf16x8 bfr[2][4];
#pragma unroll
    for (int nt = 0; nt < 2; ++nt) {
        const float* p = e1g + (size_t)(n0 + 16 * nt + l15) * DDIM + q * 8;
#pragma unroll
        for (int k4 = 0; k4 < 4; ++k4) {
            float4 u0 = *(const float4*)(p + k4 * 32);
            float4 u1 = *(const float4*)(p + k4 * 32 + 4);
            union { ushort4 h[2]; bf16x8 v; } cv;
            cv.h[0] = f2bf4(u0);
            cv.h[1] = f2bf4(u1);
            bfr[nt][k4] = cv.v;
        }
    }

    // e2 pinned: e2v[nt][et] = e2[n0+16nt+l15][16et+4q .. +4)
    f32x4 e2v[2][8];
#pragma unroll
    for (int nt = 0; nt < 2; ++nt) {
        const float* p = e2g + (size_t)(n0 + 16 * nt + l15) * DDIM + 4 * q;
#pragma unroll
        for (int et = 0; et < 8; ++et)
            e2v[nt][et] = *(const f32x4*)(p + 16 * et);
    }

    const int rel0 = rels[na];
    const int rel1 = rels[nb];

    // online softmax state (per lane, 2 rows)
    float m0 = -1e30f, se0 = 0.f, pn0 = 0.f, lr0 = 0.f;
    float m1 = -1e30f, se1 = 0.f, pn1 = 0.f, lr1 = 0.f;

    const unsigned short* ab = Cth + l15 * DDIM + q * 8;

#pragma unroll 1
    for (int r = 0; r < RCLS; ++r) {
        float s0 = 0.f, s1 = 0.f;
#pragma unroll
        for (int et = 0; et < 8; ++et) {
            f32x4 acc0 = {0.f, 0.f, 0.f, 0.f};
            f32x4 acc1 = {0.f, 0.f, 0.f, 0.f};
#pragma unroll
            for (int k4 = 0; k4 < 4; ++k4) {
                bf16x8 af = *(const bf16x8*)(ab + et * (16 * DDIM) + k4 * 32);
                acc0 = __builtin_amdgcn_mfma_f32_16x16x32_bf16(af, bfr[0][k4], acc0, 0, 0, 0);
                acc1 = __builtin_amdgcn_mfma_f32_16x16x32_bf16(af, bfr[1][k4], acc1, 0, 0, 0);
            }
            f32x4 t0 = acc0 * e2v[0][et];
            f32x4 t1 = acc1 * e2v[1][et];
            s0 += t0[0] + t0[1] + t0[2] + t0[3];
            s1 += t1[0] + t1[1] + t1[2] + t1[3];
        }
        // reduce over the 4 q-groups (e-span); all lanes end with full logit
        s0 += __shfl_xor(s0, 16); s0 += __shfl_xor(s0, 32);
        s1 += __shfl_xor(s1, 16); s1 += __shfl_xor(s1, 32);

        // online softmax update
        float wr = (float)(r + 1);
        float nm0 = fmaxf(m0, s0);
        float c0 = __expf(m0 - nm0), e0 = __expf(s0 - nm0);
        se0 = se0 * c0 + e0;  pn0 = pn0 * c0 + wr * e0;  m0 = nm0;
        if (r == rel0) lr0 = s0;
        float nm1 = fmaxf(m1, s1);
        float c1 = __expf(m1 - nm1), e1 = __expf(s1 - nm1);
        se1 = se1 * c1 + e1;  pn1 = pn1 * c1 + wr * e1;  m1 = nm1;
        if (r == rel1) lr1 = s1;

        ab += 16384;
    }

    // epilogue: every lane has both rows' state; q==0 lanes store
    if (q == 0) {
        out[1 + na] = pn0 / se0;
        out[1 + nb] = pn1 / se1;
    }
    float lossc = (q == 0)
        ? -((lr0 - m0 - logf(se0)) + (lr1 - m1 - logf(se1))) * inv_n
        : 0.f;
#pragma unroll
    for (int mm = 1; mm <= 32; mm <<= 1) lossc += __shfl_xor(lossc, mm);
    if (lane == 0) loss_ws[tile] = lossc;
}

// ---- final: reduce the per-wave partials into out[0] ----
__global__ __launch_bounds__(256) void loss_reduce_kernel(
    const float* __restrict__ loss_ws, float* __restrict__ out)
{
    __shared__ float s[4];
    float v = 0.0f;
    for (int i = threadIdx.x; i < NTILE; i += 256) v += loss_ws[i];
#pragma unroll
    for (int m = 1; m <= 32; m <<= 1) v += __shfl_xor(v, m);
    if ((threadIdx.x & 63) == 0) s[threadIdx.x >> 6] = v;
    __syncthreads();
    if (threadIdx.x == 0) out[0] = s[0] + s[1] + s[2] + s[3];
}

extern "C" void kernel_launch(void* const* d_in, const int* in_sizes, int n_in,
                              void* d_out, int out_size, void* d_ws, size_t ws_size,
                              hipStream_t stream) {
    const float* e1   = (const float*)d_in[0];
    const float* e2   = (const float*)d_in[1];
    const float* rele = (const float*)d_in[2];
    const float* wsc  = (const float*)d_in[3];
    const int*   rels = (const int*)d_in[4];
    float* out = (float*)d_out;

    unsigned short* Cth = (unsigned short*)d_ws;             // 163840 B
    float* loss_ws = (float*)((char*)d_ws + 163840);         // 16384 B

    prep_kernel<<<80, 256, 0, stream>>>(rele, wsc, Cth);
    bilinear_mfma_kernel<<<GRID2, 256, 0, stream>>>(
        e1, e2, Cth, rels, out, loss_ws, 1.0f / (float)NTOT);
    loss_reduce_kernel<<<1, 256, 0, stream>>>(loss_ws, out);
}

// Round 8
// 170.042 us; speedup vs baseline: 1.3593x; 1.3593x over previous
//
#include <hip/hip_runtime.h>
#include <stdint.h>

// Problem: N=131072, D=128, W=16, R=5
//   logit[n,r] = e1[n]^T C_r e2[n],  C_r = sum_w weight[w,r] * M_w
//   out[0] = -mean(log_softmax(logit)[n, rels[n]]),  out[1..N] = expected rating
//
// R16: Cth in LDS + 16-wave blocks.
//   R15 post-mortem: L2-serving the A-frag stream (160KB/wave) + 2-chain ILP
//   = latency exposure; all rounds stuck at ~8 waves/CU effective.
//   This round: 1024-thread blocks (16 waves, 1 block/CU, VGPR<=128 forced
//   by block shape -> whole block resident), r=0..3 of Cth staged into
//   128 KiB LDS (m201 precedent) XOR-swizzled (byte ^= ((row&7)<<4): the
//   16-lane same-column ds_read_b128 pattern goes 16-way -> 2-way = free),
//   r=4 streamed from L2 (32KB hot, issued at et-top, covered by 16 MFMAs).
//   Wave-autonomous 32 rows, et-outer/r-inner: 10 MFMA chains per et.
//   One barrier per KERNEL per block. Tells: LDS 131072, VGPR<=128,
//   BANK_CONFLICT ~0, WRITE_SIZE ~600KB.

#define NTOT 131072
#define DDIM 128
#define WBAS 16
#define RCLS 5
#define ROWS 32                  // rows per wave
#define WAVES 16                 // waves per block
#define RPB  (WAVES * ROWS)      // 512 rows per block
#define GRID2 (NTOT / RPB)       // 256 blocks
#define NTILE2 (NTOT / ROWS)     // 4096 wave-tiles

typedef __attribute__((ext_vector_type(8))) short bf16x8;
typedef __attribute__((ext_vector_type(4))) float f32x4;

__device__ __forceinline__ unsigned short f2bf(float x) {
    union { float f; unsigned u; } v; v.f = x;
    unsigned u = v.u + 0x7FFFu + ((v.u >> 16) & 1u);
    return (unsigned short)(u >> 16);
}

__device__ __forceinline__ ushort4 f2bf4(float4 v) {
    return make_ushort4(f2bf(v.x), f2bf(v.y), f2bf(v.z), f2bf(v.w));
}

// ---- prep: coalesced read (lanes along e), LDS transpose, bf16 ----
// grid = 80 blocks: r = bx>>4 (5), d-band d0 = (bx&15)*8 (16)
__global__ __launch_bounds__(256) void prep_kernel(
    const float* __restrict__ rel_embeds,    // [W][d][e]
    const float* __restrict__ wsc,           // [W][R]
    unsigned short* __restrict__ Cth)        // [R][e][d] bf16
{
    __shared__ float tile[8][129];
    const int bx = blockIdx.x;
    const int r  = bx >> 4;
    const int d0 = (bx & 15) << 3;
    const int t  = threadIdx.x;

    const int e  = t & 127;     // lanes consecutive in e -> coalesced reads
    const int dl = t >> 7;      // 0..1

    float acc[4] = {0.f, 0.f, 0.f, 0.f};
    for (int w = 0; w < WBAS; ++w) {
        float s = wsc[w * RCLS + r];
#pragma unroll
        for (int dd = 0; dd < 4; ++dd)
            acc[dd] += s * rel_embeds[w * 16384 + (d0 + dd * 2 + dl) * 128 + e];
    }
#pragma unroll
    for (int dd = 0; dd < 4; ++dd) tile[dd * 2 + dl][e] = acc[dd];
    __syncthreads();

    if (t < 128) {          // thread t -> output column e=t, all 8 d of the band
        unsigned short h[8];
#pragma unroll
        for (int j = 0; j < 8; ++j) h[j] = f2bf(tile[j][t]);
        size_t base = (size_t)r * 16384 + (size_t)t * 128 + d0;   // 16B aligned
        *(ushort4*)(Cth + base)     = make_ushort4(h[0], h[1], h[2], h[3]);
        *(ushort4*)(Cth + base + 4) = make_ushort4(h[4], h[5], h[6], h[7]);
    }
}

// ---- main: 1024 threads / 16 waves, Cth r=0..3 in swizzled LDS ----
__global__ __launch_bounds__(1024) void bilinear_mfma_kernel(
    const float* __restrict__ e1g,           // [N, D]
    const float* __restrict__ e2g,           // [N, D]
    const unsigned short* __restrict__ Cth,  // [R, 128(e), 128(d)] bf16
    const int*   __restrict__ rels,
    float* __restrict__ out,                 // [1 + N]
    float* __restrict__ loss_ws,             // [NTILE2] per-wave loss partials
    float inv_n)
{
    __shared__ __align__(16) unsigned short s_c[65536];  // 128 KiB: Cth r=0..3

    const int tid  = threadIdx.x;            // 0..1023
    const int lane = tid & 63;
    const int w    = tid >> 6;               // wave 0..15
    const int l15  = lane & 15;
    const int q    = lane >> 4;

    // ---- stage Cth[r=0..3] -> LDS, XOR-swizzled ----
    // granule gi = 16B; A = gi*16; row bits (A>>8)&7 = e&7; swizzle bits 4-6.
#pragma unroll
    for (int j = 0; j < 8; ++j) {
        int gi = j * 1024 + tid;
        uint4 v = *(const uint4*)(Cth + gi * 8);
        int A  = gi * 16;
        int As = A ^ (((A >> 8) & 7) << 4);
        *(uint4*)((char*)s_c + As) = v;
    }

    const int n0 = blockIdx.x * RPB + w * ROWS;
    const int na = n0 + l15;                 // row for tile nt=0
    const int nb = n0 + 16 + l15;            // row for tile nt=1

    // B-fragments from e1 (f32 -> bf16 in regs), pinned: 32 VGPR.
    bf16x8 bfr[2][4];
#pragma unroll
    for (int nt = 0; nt < 2; ++nt) {
        const float* p = e1g + (size_t)(n0 + 16 * nt + l15) * DDIM + q * 8;
#pragma unroll
        for (int k4 = 0; k4 < 4; ++k4) {
            float4 u0 = *(const float4*)(p + k4 * 32);
            float4 u1 = *(const float4*)(p + k4 * 32 + 4);
            union { ushort4 h[2]; bf16x8 v; } cv;
            cv.h[0] = f2bf4(u0);
            cv.h[1] = f2bf4(u1);
            bfr[nt][k4] = cv.v;
        }
    }

    const int rel0 = rels[na];
    const int rel1 = rels[nb];

    __syncthreads();   // the ONLY block-wide barrier

    float s0[RCLS] = {0.f, 0.f, 0.f, 0.f, 0.f};
    float s1[RCLS] = {0.f, 0.f, 0.f, 0.f, 0.f};

    const int sw = (l15 & 7) << 4;                       // swizzle for reads
    const char* rowb = (const char*)s_c + l15 * 256;     // row e = et*16+l15
    const unsigned short* ab4 = Cth + 4 * 16384 + l15 * DDIM + q * 8;  // r=4, L2

#pragma unroll 1
    for (int et = 0; et < 8; ++et) {
        // r=4 A-frags from L2: issue first, consumed last in this et-iter
        bf16x8 ag[4];
#pragma unroll
        for (int k4 = 0; k4 < 4; ++k4)
            ag[k4] = *(const bf16x8*)(ab4 + et * 2048 + k4 * 32);

        f32x4 e2a = *(const f32x4*)(e2g + (size_t)na * DDIM + et * 16 + q * 4);
        f32x4 e2b = *(const f32x4*)(e2g + (size_t)nb * DDIM + et * 16 + q * 4);

        const char* rb = rowb + et * 4096;   // + et*16 rows * 256 B
#pragma unroll
        for (int r = 0; r < 4; ++r) {
            bf16x8 af[4];
#pragma unroll
            for (int k4 = 0; k4 < 4; ++k4)
                af[k4] = *(const bf16x8*)(rb + r * 32768 + ((q * 16 + k4 * 64) ^ sw));
            f32x4 acc0 = {0.f, 0.f, 0.f, 0.f};
            f32x4 acc1 = {0.f, 0.f, 0.f, 0.f};
#pragma unroll
            for (int k4 = 0; k4 < 4; ++k4) {
                acc0 = __builtin_amdgcn_mfma_f32_16x16x32_bf16(af[k4], bfr[0][k4], acc0, 0, 0, 0);
                acc1 = __builtin_amdgcn_mfma_f32_16x16x32_bf16(af[k4], bfr[1][k4], acc1, 0, 0, 0);
            }
            f32x4 t0 = acc0 * e2a;
            f32x4 t1 = acc1 * e2b;
            s0[r] += t0[0] + t0[1] + t0[2] + t0[3];
            s1[r] += t1[0] + t1[1] + t1[2] + t1[3];
        }
        {   // r = 4 from the early global loads
            f32x4 acc0 = {0.f, 0.f, 0.f, 0.f};
            f32x4 acc1 = {0.f, 0.f, 0.f, 0.f};
#pragma unroll
            for (int k4 = 0; k4 < 4; ++k4) {
                acc0 = __builtin_amdgcn_mfma_f32_16x16x32_bf16(ag[k4], bfr[0][k4], acc0, 0, 0, 0);
                acc1 = __builtin_amdgcn_mfma_f32_16x16x32_bf16(ag[k4], bfr[1][k4], acc1, 0, 0, 0);
            }
            f32x4 t0 = acc0 * e2a;
            f32x4 t1 = acc1 * e2b;
            s0[4] += t0[0] + t0[1] + t0[2] + t0[3];
            s1[4] += t1[0] + t1[1] + t1[2] + t1[3];
        }
    }

    // reduce over the 4 q-groups (e-span); all lanes end with full logits
#pragma unroll
    for (int r = 0; r < RCLS; ++r) {
        s0[r] += __shfl_xor(s0[r], 16); s0[r] += __shfl_xor(s0[r], 32);
        s1[r] += __shfl_xor(s1[r], 16); s1[r] += __shfl_xor(s1[r], 32);
    }

    // softmax epilogue (per lane, 2 rows); rel-gather via unrolled select
    float m0 = s0[0], m1 = s1[0];
#pragma unroll
    for (int r = 1; r < RCLS; ++r) { m0 = fmaxf(m0, s0[r]); m1 = fmaxf(m1, s1[r]); }
    float se0 = 0.f, pn0 = 0.f, lr0 = 0.f;
    float se1 = 0.f, pn1 = 0.f, lr1 = 0.f;
#pragma unroll
    for (int r = 0; r < RCLS; ++r) {
        float e0 = __expf(s0[r] - m0);
        float e1v = __expf(s1[r] - m1);
        se0 += e0;  pn0 += (float)(r + 1) * e0;
        se1 += e1v; pn1 += (float)(r + 1) * e1v;
        if (r == rel0) lr0 = s0[r];
        if (r == rel1) lr1 = s1[r];
    }
    if (q == 0) {
        out[1 + na] = pn0 / se0;
        out[1 + nb] = pn1 / se1;
    }
    float lossc = (q == 0)
        ? -((lr0 - m0 - logf(se0)) + (lr1 - m1 - logf(se1))) * inv_n
        : 0.f;
#pragma unroll
    for (int mm = 1; mm <= 32; mm <<= 1) lossc += __shfl_xor(lossc, mm);
    if (lane == 0) loss_ws[blockIdx.x * WAVES + w] = lossc;
}

// ---- final: reduce the per-wave partials into out[0] ----
__global__ __launch_bounds__(256) void loss_reduce_kernel(
    const float* __restrict__ loss_ws, float* __restrict__ out)
{
    __shared__ float s[4];
    float v = 0.0f;
    for (int i = threadIdx.x; i < NTILE2; i += 256) v += loss_ws[i];
#pragma unroll
    for (int m = 1; m <= 32; m <<= 1) v += __shfl_xor(v, m);
    if ((threadIdx.x & 63) == 0) s[threadIdx.x >> 6] = v;
    __syncthreads();
    if (threadIdx.x == 0) out[0] = s[0] + s[1] + s[2] + s[3];
}

extern "C" void kernel_launch(void* const* d_in, const int* in_sizes, int n_in,
                              void* d_out, int out_size, void* d_ws, size_t ws_size,
                              hipStream_t stream) {
    const float* e1   = (const float*)d_in[0];
    const float* e2   = (const float*)d_in[1];
    const float* rele = (const float*)d_in[2];
    const float* wsc  = (const float*)d_in[3];
    const int*   rels = (const int*)d_in[4];
    float* out = (float*)d_out;

    unsigned short* Cth = (unsigned short*)d_ws;             // 163840 B
    float* loss_ws = (float*)((char*)d_ws + 163840);         // 16384 B

    prep_kernel<<<80, 256, 0, stream>>>(rele, wsc, Cth);
    bilinear_mfma_kernel<<<GRID2, 1024, 0, stream>>>(
        e1, e2, Cth, rels, out, loss_ws, 1.0f / (float)NTOT);
    loss_reduce_kernel<<<1, 256, 0, stream>>>(loss_ws, out);
}

// Round 9
// 168.393 us; speedup vs baseline: 1.3726x; 1.0098x over previous
//
#include <hip/hip_runtime.h>
#include <stdint.h>

// Problem: N=131072, D=128, W=16, R=5
//   logit[n,r] = e1[n]^T C_r e2[n],  C_r = sum_w weight[w,r] * M_w
//   out[0] = -mean(log_softmax(logit)[n, rels[n]]),  out[1..N] = expected rating
//
// R17: ALL of Cth in LDS (163840 B = exactly the 160 KiB pool) + e2
//   software-pipelined one et ahead.
//   R16 (55us, best) left two latency sources in the et-loop: r=4 A-frags
//   from L2, and e2 loaded immediately before use (~200-400cyc exposed per
//   et per wave). Now the steady-state loop has ZERO VMEM: 20 ds_read_b128
//   + 40 MFMA + contract per et. e2 dbuf costs 8 regs (vs 64 for a full
//   pin -- 1024-thread blocks hard-cap VGPR at 128). Staging 128->160 KiB,
//   same bijective swizzle (bits 4-6 ^= e&7; r*32768 doesn't touch bits
//   8-10). Per-CU model: DS 31k cyc (12.8us floor), MFMA 6.2k, VALU ~8k.
//   Tells: LDS_Block_Size=163840 (launch), VGPR<=128, WRITE~540KB (spill).

#define NTOT 131072
#define DDIM 128
#define WBAS 16
#define RCLS 5
#define ROWS 32                  // rows per wave
#define WAVES 16                 // waves per block
#define RPB  (WAVES * ROWS)      // 512 rows per block
#define GRID2 (NTOT / RPB)       // 256 blocks
#define NTILE2 (NTOT / ROWS)     // 4096 wave-tiles

typedef __attribute__((ext_vector_type(8))) short bf16x8;
typedef __attribute__((ext_vector_type(4))) float f32x4;

__device__ __forceinline__ unsigned short f2bf(float x) {
    union { float f; unsigned u; } v; v.f = x;
    unsigned u = v.u + 0x7FFFu + ((v.u >> 16) & 1u);
    return (unsigned short)(u >> 16);
}

__device__ __forceinline__ ushort4 f2bf4(float4 v) {
    return make_ushort4(f2bf(v.x), f2bf(v.y), f2bf(v.z), f2bf(v.w));
}

// ---- prep: coalesced read (lanes along e), LDS transpose, bf16 ----
// grid = 80 blocks: r = bx>>4 (5), d-band d0 = (bx&15)*8 (16)
__global__ __launch_bounds__(256) void prep_kernel(
    const float* __restrict__ rel_embeds,    // [W][d][e]
    const float* __restrict__ wsc,           // [W][R]
    unsigned short* __restrict__ Cth)        // [R][e][d] bf16
{
    __shared__ float tile[8][129];
    const int bx = blockIdx.x;
    const int r  = bx >> 4;
    const int d0 = (bx & 15) << 3;
    const int t  = threadIdx.x;

    const int e  = t & 127;     // lanes consecutive in e -> coalesced reads
    const int dl = t >> 7;      // 0..1

    float acc[4] = {0.f, 0.f, 0.f, 0.f};
    for (int w = 0; w < WBAS; ++w) {
        float s = wsc[w * RCLS + r];
#pragma unroll
        for (int dd = 0; dd < 4; ++dd)
            acc[dd] += s * rel_embeds[w * 16384 + (d0 + dd * 2 + dl) * 128 + e];
    }
#pragma unroll
    for (int dd = 0; dd < 4; ++dd) tile[dd * 2 + dl][e] = acc[dd];
    __syncthreads();

    if (t < 128) {          // thread t -> output column e=t, all 8 d of the band
        unsigned short h[8];
#pragma unroll
        for (int j = 0; j < 8; ++j) h[j] = f2bf(tile[j][t]);
        size_t base = (size_t)r * 16384 + (size_t)t * 128 + d0;   // 16B aligned
        *(ushort4*)(Cth + base)     = make_ushort4(h[0], h[1], h[2], h[3]);
        *(ushort4*)(Cth + base + 4) = make_ushort4(h[4], h[5], h[6], h[7]);
    }
}

// ---- main: 1024 threads / 16 waves, ALL of Cth in swizzled LDS ----
__global__ __launch_bounds__(1024) void bilinear_mfma_kernel(
    const float* __restrict__ e1g,           // [N, D]
    const float* __restrict__ e2g,           // [N, D]
    const unsigned short* __restrict__ Cth,  // [R, 128(e), 128(d)] bf16
    const int*   __restrict__ rels,
    float* __restrict__ out,                 // [1 + N]
    float* __restrict__ loss_ws,             // [NTILE2] per-wave loss partials
    float inv_n)
{
    __shared__ __align__(16) unsigned short s_c[81920];  // 160 KiB: all of Cth

    const int tid  = threadIdx.x;            // 0..1023
    const int lane = tid & 63;
    const int w    = tid >> 6;               // wave 0..15
    const int l15  = lane & 15;
    const int q    = lane >> 4;

    const int n0 = blockIdx.x * RPB + w * ROWS;
    const int na = n0 + l15;                 // row for tile nt=0
    const int nb = n0 + 16 + l15;            // row for tile nt=1

    // B-fragments from e1 (f32 -> bf16 in regs), pinned: 32 VGPR.
    bf16x8 bfr[2][4];
#pragma unroll
    for (int nt = 0; nt < 2; ++nt) {
        const float* p = e1g + (size_t)(n0 + 16 * nt + l15) * DDIM + q * 8;
#pragma unroll
        for (int k4 = 0; k4 < 4; ++k4) {
            float4 u0 = *(const float4*)(p + k4 * 32);
            float4 u1 = *(const float4*)(p + k4 * 32 + 4);
            union { ushort4 h[2]; bf16x8 v; } cv;
            cv.h[0] = f2bf4(u0);
            cv.h[1] = f2bf4(u1);
            bfr[nt][k4] = cv.v;
        }
    }

    const int rel0 = rels[na];
    const int rel1 = rels[nb];

    // ---- stage ALL of Cth -> LDS, XOR-swizzled ----
    // granule gi = 16B; A = gi*16; row bits (A>>8)&7 = e&7; swizzle bits 4-6.
    // (r*32768 contributes nothing to bits 8-10 -> same formula all planes.)
#pragma unroll
    for (int j = 0; j < 10; ++j) {
        int gi = j * 1024 + tid;
        uint4 v = *(const uint4*)(Cth + gi * 8);
        int A  = gi * 16;
        int As = A ^ (((A >> 8) & 7) << 4);
        *(uint4*)((char*)s_c + As) = v;
    }

    __syncthreads();   // the ONLY block-wide barrier

    float s0[RCLS] = {0.f, 0.f, 0.f, 0.f, 0.f};
    float s1[RCLS] = {0.f, 0.f, 0.f, 0.f, 0.f};

    const int sw = (l15 & 7) << 4;                       // swizzle for reads
    const char* rowb = (const char*)s_c + l15 * 256;     // row e = et*16+l15
    const float* e2pa = e2g + (size_t)na * DDIM + q * 4;
    const float* e2pb = e2g + (size_t)nb * DDIM + q * 4;

    // e2 pipeline: load et=0 now; inside the loop issue et+1 before compute
    f32x4 e2a = *(const f32x4*)(e2pa);
    f32x4 e2b = *(const f32x4*)(e2pb);

#pragma unroll 1
    for (int et = 0; et < 8; ++et) {
        // issue next et's e2 first (consumed one full iteration later)
        f32x4 e2an, e2bn;
        if (et < 7) {
            e2an = *(const f32x4*)(e2pa + (et + 1) * 16);
            e2bn = *(const f32x4*)(e2pb + (et + 1) * 16);
        }

        const char* rb = rowb + et * 4096;   // + et*16 rows * 256 B
#pragma unroll
        for (int r = 0; r < RCLS; ++r) {
            bf16x8 af[4];
#pragma unroll
            for (int k4 = 0; k4 < 4; ++k4)
                af[k4] = *(const bf16x8*)(rb + r * 32768 + ((q * 16 + k4 * 64) ^ sw));
            f32x4 acc0 = {0.f, 0.f, 0.f, 0.f};
            f32x4 acc1 = {0.f, 0.f, 0.f, 0.f};
#pragma unroll
            for (int k4 = 0; k4 < 4; ++k4) {
                acc0 = __builtin_amdgcn_mfma_f32_16x16x32_bf16(af[k4], bfr[0][k4], acc0, 0, 0, 0);
                acc1 = __builtin_amdgcn_mfma_f32_16x16x32_bf16(af[k4], bfr[1][k4], acc1, 0, 0, 0);
            }
            f32x4 t0 = acc0 * e2a;
            f32x4 t1 = acc1 * e2b;
            s0[r] += t0[0] + t0[1] + t0[2] + t0[3];
            s1[r] += t1[0] + t1[1] + t1[2] + t1[3];
        }
        e2a = e2an;
        e2b = e2bn;
    }

    // reduce over the 4 q-groups (e-span); all lanes end with full logits
#pragma unroll
    for (int r = 0; r < RCLS; ++r) {
        s0[r] += __shfl_xor(s0[r], 16); s0[r] += __shfl_xor(s0[r], 32);
        s1[r] += __shfl_xor(s1[r], 16); s1[r] += __shfl_xor(s1[r], 32);
    }

    // softmax epilogue (per lane, 2 rows); rel-gather via unrolled select
    float m0 = s0[0], m1 = s1[0];
#pragma unroll
    for (int r = 1; r < RCLS; ++r) { m0 = fmaxf(m0, s0[r]); m1 = fmaxf(m1, s1[r]); }
    float se0 = 0.f, pn0 = 0.f, lr0 = 0.f;
    float se1 = 0.f, pn1 = 0.f, lr1 = 0.f;
#pragma unroll
    for (int r = 0; r < RCLS; ++r) {
        float e0 = __expf(s0[r] - m0);
        float e1v = __expf(s1[r] - m1);
        se0 += e0;  pn0 += (float)(r + 1) * e0;
        se1 += e1v; pn1 += (float)(r + 1) * e1v;
        if (r == rel0) lr0 = s0[r];
        if (r == rel1) lr1 = s1[r];
    }
    if (q == 0) {
        out[1 + na] = pn0 / se0;
        out[1 + nb] = pn1 / se1;
    }
    float lossc = (q == 0)
        ? -((lr0 - m0 - logf(se0)) + (lr1 - m1 - logf(se1))) * inv_n
        : 0.f;
#pragma unroll
    for (int mm = 1; mm <= 32; mm <<= 1) lossc += __shfl_xor(lossc, mm);
    if (lane == 0) loss_ws[blockIdx.x * WAVES + w] = lossc;
}

// ---- final: reduce the per-wave partials into out[0] ----
__global__ __launch_bounds__(256) void loss_reduce_kernel(
    const float* __restrict__ loss_ws, float* __restrict__ out)
{
    __shared__ float s[4];
    float v = 0.0f;
    for (int i = threadIdx.x; i < NTILE2; i += 256) v += loss_ws[i];
#pragma unroll
    for (int m = 1; m <= 32; m <<= 1) v += __shfl_xor(v, m);
    if ((threadIdx.x & 63) == 0) s[threadIdx.x >> 6] = v;
    __syncthreads();
    if (threadIdx.x == 0) out[0] = s[0] + s[1] + s[2] + s[3];
}

extern "C" void kernel_launch(void* const* d_in, const int* in_sizes, int n_in,
                              void* d_out, int out_size, void* d_ws, size_t ws_size,
                              hipStream_t stream) {
    const float* e1   = (const float*)d_in[0];
    const float* e2   = (const float*)d_in[1];
    const float* rele = (const float*)d_in[2];
    const float* wsc  = (const float*)d_in[3];
    const int*   rels = (const int*)d_in[4];
    float* out = (float*)d_out;

    unsigned short* Cth = (unsigned short*)d_ws;             // 163840 B
    float* loss_ws = (float*)((char*)d_ws + 163840);         // 16384 B

    prep_kernel<<<80, 256, 0, stream>>>(rele, wsc, Cth);
    bilinear_mfma_kernel<<<GRID2, 1024, 0, stream>>>(
        e1, e2, Cth, rels, out, loss_ws, 1.0f / (float)NTOT);
    loss_reduce_kernel<<<1, 256, 0, stream>>>(loss_ws, out);
}